// Round 6
// baseline (379.913 us; speedup 1.0000x reference)
//
#include <hip/hip_runtime.h>

#define BB 16
#define CC 128
#define HH 64
#define WW 64
#define NG 8
#define WPB 147456       // 128*128*9 weights per sample
#define PLANE 4096       // 64*64
#define GROUP_N 65536.f  // 16 ch * 4096 px

typedef __attribute__((ext_vector_type(8))) short short8;
typedef __attribute__((ext_vector_type(4))) float floatx4;
typedef __attribute__((ext_vector_type(4))) unsigned short ushortx4;

__device__ __forceinline__ unsigned short f2bf(float f) {
    unsigned u = __builtin_bit_cast(unsigned, f);
    return (unsigned short)((u + 0x7fffu + ((u >> 16) & 1u)) >> 16);
}
__device__ __forceinline__ float bf2f(unsigned short h) {
    unsigned u = ((unsigned)h) << 16;
    return __builtin_bit_cast(float, u);
}

// ---------- device helpers --------------------------------------------------

// stream_gemm body (best measured GEMM structure): one head, one n-column per
// thread, 8-deep scalar loads, z via wave-uniform s_loads. gblk in [0,576).
__device__ __forceinline__ void gemm_head(int gblk, int tid,
                                          const float* __restrict__ z,
                                          const float* __restrict__ hw,
                                          const float* __restrict__ hb,
                                          unsigned short* __restrict__ pw)
{
    const int n = gblk * 256 + tid;
    float acc[BB];
#pragma unroll
    for (int b = 0; b < BB; ++b) acc[b] = 0.f;

    for (int k0 = 0; k0 < 128; k0 += 8) {
        float hv[8];
#pragma unroll
        for (int u = 0; u < 8; ++u) hv[u] = hw[(size_t)(k0 + u) * WPB + n];
#pragma unroll
        for (int u = 0; u < 8; ++u) {
#pragma unroll
            for (int b = 0; b < BB; ++b)
                acc[b] = fmaf(z[b * 128 + k0 + u], hv[u], acc[b]);
        }
    }
    const float bias = hb[n];
#pragma unroll
    for (int b = 0; b < BB; ++b)
        pw[(size_t)b * WPB + n] = f2bf(acc[b] + bias);
}

// repack one head: plain P[b][n] -> Wf[b][icc][tap][frag][lane][j]
// oc=frag*16+(lane&15), ic=icc*32+(lane>>4)*8+j. gid in [0,32768).
__device__ __forceinline__ void repack_head(int gid,
                                            const unsigned short* __restrict__ P,
                                            unsigned short* __restrict__ wf)
{
    int lane = gid & 63, frag = (gid >> 6) & 7, icc = (gid >> 9) & 3, b = gid >> 11;
    const unsigned short* src = P + (size_t)b * WPB
        + (frag * 16 + (lane & 15)) * 1152 + (icc * 32 + (lane >> 4) * 8) * 9;
    unsigned short buf[72];
#pragma unroll
    for (int i = 0; i < 9; ++i)
        *(short8*)(buf + i * 8) = *(const short8*)(src + i * 8);  // 16B-aligned
#pragma unroll
    for (int tap = 0; tap < 9; ++tap) {
        short8 o;
#pragma unroll
        for (int j = 0; j < 8; ++j) o[j] = (short)buf[j * 9 + tap];
        size_t off = ((((size_t)(b * 4 + icc) * 9 + tap) * 8 + frag) * 64 + lane) * 8;
        *(short8*)(wf + off) = o;
    }
}

// MFMA conv body: 9 tap-shifted GEMMs over 4 ic-chunks. blk in [0,512).
// MODE 0: write bf16 Xt layout + stats ; MODE 1: write fp32 NCHW + stats
template <int MODE>
__device__ __forceinline__ void conv_body(int blk, int tid,
                                          const unsigned short* __restrict__ xt,
                                          const unsigned short* __restrict__ wf,
                                          unsigned short* __restrict__ yt,
                                          float* __restrict__ ynchw,
                                          float* __restrict__ stats)
{
    const int b = blk >> 5, tile = blk & 31;
    const int w = tid >> 6, lane = tid & 63;
    const int i = w >> 1, j = w & 1;     // m-half, row-within-tile
    const int q = lane >> 4, n16 = lane & 15;
    const int y = tile * 2 + j;

    floatx4 acc[4][4];
#pragma unroll
    for (int mf = 0; mf < 4; ++mf)
#pragma unroll
        for (int nf = 0; nf < 4; ++nf) acc[mf][nf] = (floatx4)0.f;

    const unsigned short* xtb_b = xt + (size_t)b * 4 * PLANE * 32;
    const unsigned short* wf_b  = wf + (size_t)b * WPB;

    for (int icc = 0; icc < 4; ++icc) {
        const unsigned short* xtb = xtb_b + (size_t)icc * PLANE * 32;
        const unsigned short* wfc = wf_b + (size_t)icc * 36864;   // 9*8*64*8
#pragma unroll
        for (int tap = 0; tap < 9; ++tap) {
            const int dy = tap / 3 - 1, dx = tap % 3 - 1;
            const int yy = y + dy;
            if ((unsigned)yy >= (unsigned)HH) continue;   // wave-uniform

            short8 a[4], bbf[4];
#pragma unroll
            for (int mf = 0; mf < 4; ++mf)
                a[mf] = *(const short8*)(wfc + (((size_t)(tap * 8 + i * 4 + mf)) * 64 + lane) * 8);
#pragma unroll
            for (int nf = 0; nf < 4; ++nf) {
                int xx = nf * 16 + n16 + dx;
                if ((unsigned)xx < (unsigned)WW)
                    bbf[nf] = *(const short8*)(xtb + ((size_t)(yy * WW + xx)) * 32 + q * 8);
                else
                    bbf[nf] = (short8)0;
            }
#pragma unroll
            for (int mf = 0; mf < 4; ++mf)
#pragma unroll
                for (int nf = 0; nf < 4; ++nf)
                    acc[mf][nf] = __builtin_amdgcn_mfma_f32_16x16x32_bf16(
                        a[mf], bbf[nf], acc[mf][nf], 0, 0, 0);
        }
    }

    // epilogue: store + fused GN stats (group g == i*4 + mf)
#pragma unroll
    for (int mf = 0; mf < 4; ++mf) {
        float s1 = 0.f, s2 = 0.f;
#pragma unroll
        for (int nf = 0; nf < 4; ++nf) {
#pragma unroll
            for (int r = 0; r < 4; ++r) {
                float v = acc[mf][nf][r];
                s1 += v; s2 += v * v;
            }
            const int xx = nf * 16 + n16;
            if (MODE == 0) {
                const int icc1 = i * 2 + (mf >> 1);
                const int v0 = (mf & 1) * 16 + q * 4;
                unsigned short* p = yt + (((size_t)(b * 4 + icc1) * PLANE) + y * WW + xx) * 32 + v0;
                ushortx4 u;
                u.x = f2bf(acc[mf][nf][0]); u.y = f2bf(acc[mf][nf][1]);
                u.z = f2bf(acc[mf][nf][2]); u.w = f2bf(acc[mf][nf][3]);
                *(ushortx4*)p = u;
            } else {
#pragma unroll
                for (int r = 0; r < 4; ++r) {
                    int oc = i * 64 + mf * 16 + q * 4 + r;
                    ynchw[(((size_t)(b * CC + oc)) * HH + y) * WW + xx] = acc[mf][nf][r];
                }
            }
        }
#pragma unroll
        for (int off = 32; off > 0; off >>= 1) {
            s1 += __shfl_down(s1, off, 64);
            s2 += __shfl_down(s2, off, 64);
        }
        if (lane == 0) {
            int g = i * 4 + mf;
            atomicAdd(&stats[(b * NG + g) * 2 + 0], s1);
            atomicAdd(&stats[(b * NG + g) * 2 + 1], s2);
        }
    }
}

// ---------- k1: GEMM head1 (blocks 0..575) + input transpose (576..4671) -----
__global__ __launch_bounds__(256)
void gemm1_transpose(const float* __restrict__ x, const float* __restrict__ z,
                     const float* __restrict__ h1w, const float* __restrict__ h1b,
                     unsigned short* __restrict__ xt, unsigned short* __restrict__ P1)
{
    const int tid = threadIdx.x;
    if (blockIdx.x < 576) {
        gemm_head(blockIdx.x, tid, z, h1w, h1b, P1);
    } else {
        int blk = blockIdx.x - 576;           // 4096 = 16b * 4icc * 64y
        int b = blk >> 8, icc = (blk >> 6) & 3, y = blk & 63;
        int xi = tid & 63, vg = tid >> 6;     // vg 0..3 -> 8 channels
        const float* src = x + (((size_t)(b * CC + icc * 32 + vg * 8)) * HH + y) * WW + xi;
        short8 o;
#pragma unroll
        for (int e = 0; e < 8; ++e) o[e] = (short)f2bf(src[(size_t)e * PLANE]);
        unsigned short* dst = xt + (((size_t)(b * 4 + icc) * PLANE) + y * WW + xi) * 32 + vg * 8;
        *(short8*)dst = o;
    }
}

// ---------- k2: repack head1 + zero stats ------------------------------------
__global__ __launch_bounds__(256)
void repack1(const unsigned short* __restrict__ P1, unsigned short* __restrict__ wf1,
             float* __restrict__ stats)
{
    if (blockIdx.x == 0) {
        stats[threadIdx.x] = 0.f;
        stats[threadIdx.x + 256] = 0.f;
    }
    repack_head(blockIdx.x * 256 + threadIdx.x, P1, wf1);
}

// ---------- k3: conv1 (blocks 0..511) || GEMM head2 (512..1087) --------------
__global__ __launch_bounds__(256, 2)
void conv1_gemm2(const unsigned short* __restrict__ xt0,
                 const unsigned short* __restrict__ wf1,
                 unsigned short* __restrict__ xt1, float* __restrict__ stats1,
                 const float* __restrict__ z,
                 const float* __restrict__ h2w, const float* __restrict__ h2b,
                 unsigned short* __restrict__ P2)
{
    if (blockIdx.x < 512)
        conv_body<0>(blockIdx.x, threadIdx.x, xt0, wf1, xt1, nullptr, stats1);
    else
        gemm_head(blockIdx.x - 512, threadIdx.x, z, h2w, h2b, P2);
}

// ---------- k4: repack head2 (blocks 0..127) || GN1+ReLU (128..4223) ---------
__global__ __launch_bounds__(256)
void repack2_norm(const unsigned short* __restrict__ P2, unsigned short* __restrict__ wf2,
                  unsigned short* __restrict__ yt, const float* __restrict__ stats,
                  const float* __restrict__ gamma, const float* __restrict__ beta)
{
    if (blockIdx.x < 128) {
        repack_head(blockIdx.x * 256 + threadIdx.x, P2, wf2);
        return;
    }
    int idx8 = (blockIdx.x - 128) * 256 + threadIdx.x;  // 1,048,576 groups of 8
    int t = idx8 >> 2;
    int bicc = t >> 12;
    int b = bicc >> 2, icc = bicc & 3;
    int cb = icc * 32 + (idx8 & 3) * 8;                 // 8 consecutive channels
    int g = cb >> 4;
    float sum = stats[(b * NG + g) * 2 + 0];
    float ssq = stats[(b * NG + g) * 2 + 1];
    float mean = sum * (1.f / GROUP_N);
    float var  = ssq * (1.f / GROUP_N) - mean * mean;
    float inv  = rsqrtf(var + 1e-5f);

    short8 d = *(short8*)(yt + (size_t)idx8 * 8);
    short8 o;
#pragma unroll
    for (int e = 0; e < 8; ++e) {
        float s = gamma[cb + e] * inv;
        float tt = beta[cb + e] - mean * s;
        float v = bf2f((unsigned short)d[e]);
        o[e] = (short)f2bf(fmaxf(v * s + tt, 0.f));
    }
    *(short8*)(yt + (size_t)idx8 * 8) = o;
}

// ---------- k5: conv2 -> d_out fp32 + stats2 ---------------------------------
__global__ __launch_bounds__(256, 2)
void conv2(const unsigned short* __restrict__ xt1,
           const unsigned short* __restrict__ wf2,
           float* __restrict__ out, float* __restrict__ stats2)
{
    conv_body<1>(blockIdx.x, threadIdx.x, xt1, wf2, nullptr, out, stats2);
}

// ---------- k6: out = relu(GN2(out) + x), in place ---------------------------
__global__ __launch_bounds__(256)
void gn_add_relu(float* __restrict__ y2, const float* __restrict__ x,
                 const float* __restrict__ stats, const float* __restrict__ gamma,
                 const float* __restrict__ beta)
{
    const int bc = blockIdx.x;
    const int b = bc >> 7, c = bc & 127;
    const int g = c >> 4;
    float sum  = stats[(b * NG + g) * 2 + 0];
    float ssq  = stats[(b * NG + g) * 2 + 1];
    float mean = sum * (1.f / GROUP_N);
    float var  = ssq * (1.f / GROUP_N) - mean * mean;
    float inv  = rsqrtf(var + 1e-5f);
    float s = gamma[c] * inv;
    float t = beta[c] - mean * s;

    size_t base = (size_t)bc * PLANE;
    float4* yp = (float4*)(y2 + base);
    const float4* xp = (const float4*)(x + base);
    for (int i = threadIdx.x; i < PLANE / 4; i += 256) {
        float4 v = yp[i], xv = xp[i];
        v.x = fmaxf(v.x * s + t + xv.x, 0.f);
        v.y = fmaxf(v.y * s + t + xv.y, 0.f);
        v.z = fmaxf(v.z * s + t + xv.z, 0.f);
        v.w = fmaxf(v.w * s + t + xv.w, 0.f);
        yp[i] = v;
    }
}

extern "C" void kernel_launch(void* const* d_in, const int* in_sizes, int n_in,
                              void* d_out, int out_size, void* d_ws, size_t ws_size,
                              hipStream_t stream)
{
    const float* x   = (const float*)d_in[0];
    const float* z   = (const float*)d_in[1];
    const float* h1w = (const float*)d_in[2];
    const float* h1b = (const float*)d_in[3];
    const float* h2w = (const float*)d_in[4];
    const float* h2b = (const float*)d_in[5];
    const float* g1  = (const float*)d_in[6];
    const float* b1  = (const float*)d_in[7];
    const float* g2  = (const float*)d_in[8];
    const float* b2  = (const float*)d_in[9];
    float* out = (float*)d_out;

    // ws: stats(2048B) | wf1(4.71MB) | wf2(4.71MB) | xt0(16.8MB) | xt1(16.8MB)
    // P1 aliases xt1 (live k1-k2; xt1 written from k3).
    // P2 lives in d_out (live k3-k4; d_out written from k5). No extra ws.
    float* stats1 = (float*)d_ws;
    float* stats2 = stats1 + 256;
    unsigned short* wf1 = (unsigned short*)((char*)d_ws + 2048);
    unsigned short* wf2 = wf1 + 2359296;
    unsigned short* xt0 = wf2 + 2359296;
    unsigned short* xt1 = xt0 + 8388608;
    unsigned short* P1  = xt1;                    // alias, dead before conv1
    unsigned short* P2  = (unsigned short*)d_out; // alias, dead before conv2

    // k1: GEMM head1 (first -> co-resident from t0) + input transpose
    gemm1_transpose<<<576 + 4096, 256, 0, stream>>>(x, z, h1w, h1b, xt0, P1);

    // k2: P1 -> wf1 fragments; zero stats1/stats2
    repack1<<<128, 256, 0, stream>>>(P1, wf1, stats1);

    // k3: conv1 (MFMA-bound) overlapped with GEMM head2 (latency-bound)
    conv1_gemm2<<<512 + 576, 256, 0, stream>>>(xt0, wf1, xt1, stats1,
                                               z, h2w, h2b, P2);

    // k4: P2 -> wf2 fragments, overlapped with GN1+ReLU on xt1
    repack2_norm<<<128 + 4096, 256, 0, stream>>>(P2, wf2, xt1, stats1, g1, b1);

    // k5: conv2 -> d_out fp32 + stats2 (overwrites P2 scratch)
    conv2<<<512, 256, 0, stream>>>(xt1, wf2, out, stats2);

    // k6: out = relu(GN2(out) + x)
    gn_add_relu<<<2048, 256, 0, stream>>>(out, x, stats2, g2, b2);
}